// Round 1
// baseline (709.465 us; speedup 1.0000x reference)
//
#include <hip/hip_runtime.h>
#include <cstddef>

#define DIM   7168
#define NEXP  256
#define NTOK  8192
#define BM    64
#define BN    64
#define BK    32
#define LDP   68   // padded LDS leading dim: 68*4B=272B, 16B-aligned for float4 reads

// ---------------- GEMM: logits[t][e] = dot(x[t,:], w[e,:]) -------------------
__global__ __launch_bounds__(256) void gemm_f32(const float* __restrict__ X,
                                                const float* __restrict__ W,
                                                float* __restrict__ L) {
  __shared__ float As[BK][LDP];   // As[k][m]
  __shared__ float Bs[BK][LDP];   // Bs[k][n]
  const int tid = threadIdx.x;
  const int bm  = blockIdx.y * BM;
  const int bn  = blockIdx.x * BN;
  const int tx  = tid & 15;       // output col group
  const int ty  = tid >> 4;       // output row group
  float acc[4][4] = {};

  for (int k0 = 0; k0 < DIM; k0 += BK) {
    // Stage A (64 rows x 32 k) and B (64 rows x 32 k); 512 float4 each, 2/thread
#pragma unroll
    for (int i = 0; i < 2; ++i) {
      const int id = tid + i * 256;
      const int r  = id >> 3;   // 0..63
      const int kq = id & 7;    // 0..7 (float4 index along k)
      const float4 va = *reinterpret_cast<const float4*>(
          X + (size_t)(bm + r) * DIM + k0 + kq * 4);
      As[kq * 4 + 0][r] = va.x; As[kq * 4 + 1][r] = va.y;
      As[kq * 4 + 2][r] = va.z; As[kq * 4 + 3][r] = va.w;
      const float4 vb = *reinterpret_cast<const float4*>(
          W + (size_t)(bn + r) * DIM + k0 + kq * 4);
      Bs[kq * 4 + 0][r] = vb.x; Bs[kq * 4 + 1][r] = vb.y;
      Bs[kq * 4 + 2][r] = vb.z; Bs[kq * 4 + 3][r] = vb.w;
    }
    __syncthreads();
#pragma unroll
    for (int k = 0; k < BK; ++k) {
      const float4 a = *reinterpret_cast<const float4*>(&As[k][ty * 4]);
      const float4 b = *reinterpret_cast<const float4*>(&Bs[k][tx * 4]);
      const float av[4] = {a.x, a.y, a.z, a.w};
      const float bv[4] = {b.x, b.y, b.z, b.w};
#pragma unroll
      for (int i = 0; i < 4; ++i)
#pragma unroll
        for (int j = 0; j < 4; ++j)
          acc[i][j] = fmaf(av[i], bv[j], acc[i][j]);
    }
    __syncthreads();
  }
#pragma unroll
  for (int i = 0; i < 4; ++i) {
    float4 o = {acc[i][0], acc[i][1], acc[i][2], acc[i][3]};
    *reinterpret_cast<float4*>(L + (size_t)(bm + ty * 4 + i) * NEXP + bn + tx * 4) = o;
  }
}

// ---------------- Routing: one wave (64 lanes) per token ---------------------
// lane holds experts [4*lane, 4*lane+3]; group g = lanes [8g, 8g+7]
__global__ __launch_bounds__(256) void routing(const float* __restrict__ L,
                                               const float* __restrict__ bias,
                                               float* __restrict__ out) {
  const int lane = threadIdx.x & 63;
  const int tok  = (int)((blockIdx.x * blockDim.x + threadIdx.x) >> 6);
  if (tok >= NTOK) return;

  const float4 v = reinterpret_cast<const float4*>(L + (size_t)tok * NEXP)[lane];

  // softmax over 256
  float m = fmaxf(fmaxf(v.x, v.y), fmaxf(v.z, v.w));
#pragma unroll
  for (int off = 32; off; off >>= 1) m = fmaxf(m, __shfl_xor(m, off));
  float s0 = expf(v.x - m), s1 = expf(v.y - m), s2 = expf(v.z - m), s3 = expf(v.w - m);
  float sum = s0 + s1 + s2 + s3;
#pragma unroll
  for (int off = 32; off; off >>= 1) sum += __shfl_xor(sum, off);
  const float inv = 1.0f / sum;
  s0 *= inv; s1 *= inv; s2 *= inv; s3 *= inv;   // original scores

  const float4 bb = reinterpret_cast<const float4*>(bias)[lane];
  float b0 = s0 + bb.x, b1 = s1 + bb.y, b2 = s2 + bb.z, b3 = s3 + bb.w;

  // per-lane top-2 of biased scores, then merge across the 8 lanes of the group
  float m1 = fmaxf(b0, b1), m2 = fminf(b0, b1);
  if (b2 > m1) { m2 = m1; m1 = b2; } else m2 = fmaxf(m2, b2);
  if (b3 > m1) { m2 = m1; m1 = b3; } else m2 = fmaxf(m2, b3);
#pragma unroll
  for (int off = 1; off < 8; off <<= 1) {
    const float o1 = __shfl_xor(m1, off);
    const float o2 = __shfl_xor(m2, off);
    if (o1 > m1) { m2 = fmaxf(m1, o2); m1 = o1; } else m2 = fmaxf(m2, o1);
  }
  const float gscore = m1 + m2;

  float gs[8];
#pragma unroll
  for (int g = 0; g < 8; ++g) gs[g] = __shfl(gscore, g * 8);

  // top-4 groups (strict > keeps lowest index on ties, matching lax.top_k)
  unsigned gsel = 0;
#pragma unroll
  for (int k = 0; k < 4; ++k) {
    float best = -INFINITY; int bi = 0;
#pragma unroll
    for (int g = 0; g < 8; ++g)
      if (!((gsel >> g) & 1u) && gs[g] > best) { best = gs[g]; bi = g; }
    gsel |= 1u << bi;
  }
  if (!((gsel >> (lane >> 3)) & 1u)) { b0 = b1 = b2 = b3 = -INFINITY; }

  // top-8 experts, descending, lowest-index tie-break
  float outw = 0.0f, outi = 0.0f;
  for (int k = 0; k < 8; ++k) {
    float bv = b0; int bi = 0;
    if (b1 > bv) { bv = b1; bi = 1; }
    if (b2 > bv) { bv = b2; bi = 2; }
    if (b3 > bv) { bv = b3; bi = 3; }
    float rv = bv; int ri = lane * 4 + bi;
#pragma unroll
    for (int off = 32; off; off >>= 1) {
      const float ov = __shfl_xor(rv, off);
      const int   oi = __shfl_xor(ri, off);
      if (ov > rv || (ov == rv && oi < ri)) { rv = ov; ri = oi; }
    }
    const int srcl = ri >> 2, slot = ri & 3;
    const float sv = (slot == 0) ? s0 : (slot == 1) ? s1 : (slot == 2) ? s2 : s3;
    const float wsel = __shfl(sv, srcl) * 2.5f;
    if (lane == k) { outw = wsel; outi = (float)ri; }
    if (lane == srcl) {
      if      (slot == 0) b0 = -INFINITY;
      else if (slot == 1) b1 = -INFINITY;
      else if (slot == 2) b2 = -INFINITY;
      else                b3 = -INFINITY;
    }
  }
  if (lane < 8) {
    out[(size_t)tok * 8 + lane] = outw;                       // weights
    out[(size_t)NTOK * 8 + (size_t)tok * 8 + lane] = outi;    // indices (as float)
  }
}

extern "C" void kernel_launch(void* const* d_in, const int* in_sizes, int n_in,
                              void* d_out, int out_size, void* d_ws, size_t ws_size,
                              hipStream_t stream) {
  const float* x    = (const float*)d_in[0];
  const float* w    = (const float*)d_in[1];
  const float* bias = (const float*)d_in[2];
  float* out    = (float*)d_out;
  float* logits = (float*)d_ws;   // 8192*256*4 = 8 MB scratch

  dim3 gridG(NEXP / BN, NTOK / BM);   // (4, 128)
  gemm_f32<<<gridG, 256, 0, stream>>>(x, w, logits);

  routing<<<NTOK / 4, 256, 0, stream>>>(logits, bias, out);   // 4 tokens/block
}

// Round 2
// 678.024 us; speedup vs baseline: 1.0464x; 1.0464x over previous
//
#include <hip/hip_runtime.h>
#include <cstddef>

#define DIM   7168
#define NEXP  256
#define NTOK  8192
#define BM    64
#define BN    64
#define BK    32
#define LDP   68   // padded LDS leading dim (dwords); 68*4B=272B keeps float4 alignment

// ---------------- GEMM: logits[t][e] = dot(x[t,:], w[e,:]) -------------------
// Split-K across blockIdx.z; each part writes its own [NTOK][NEXP] buffer.
__global__ __launch_bounds__(256) void gemm_f32(const float* __restrict__ X,
                                                const float* __restrict__ W,
                                                float* __restrict__ L,
                                                int tiles_per_part) {
  __shared__ float As[BK][LDP];   // As[k][m]
  __shared__ float Bs[BK][LDP];   // Bs[k][n]
  const int tid = threadIdx.x;
  const int bm  = blockIdx.y * BM;
  const int bn  = blockIdx.x * BN;
  const int k_base = blockIdx.z * tiles_per_part * BK;
  float* Lp = L + (size_t)blockIdx.z * NTOK * NEXP;

  const int tx = tid & 15;        // output col group
  const int ty = tid >> 4;        // output row group

  // staging role: 128 threads stage A (4x4 register transpose), 128 stage B
  const bool isB = tid >= 128;
  const int  t   = tid & 127;
  const int  r4  = t >> 3;        // 0..15 -> rows r4*4 .. r4*4+3
  const int  kq  = t & 7;         // 0..7  -> k chunk kq*4 .. kq*4+3
  const float* src = isB ? (W + (size_t)(bn + r4 * 4) * DIM)
                         : (X + (size_t)(bm + r4 * 4) * DIM);
  float (*dst)[LDP] = isB ? Bs : As;

  float acc[4][4] = {};

  for (int it = 0; it < tiles_per_part; ++it) {
    const int k0 = k_base + it * BK + kq * 4;
    // global loads issued before the barrier: overlap with previous compute
    const float4 v0 = *reinterpret_cast<const float4*>(src + 0 * DIM + k0);
    const float4 v1 = *reinterpret_cast<const float4*>(src + 1 * DIM + k0);
    const float4 v2 = *reinterpret_cast<const float4*>(src + 2 * DIM + k0);
    const float4 v3 = *reinterpret_cast<const float4*>(src + 3 * DIM + k0);
    __syncthreads();   // previous tile fully consumed
    *reinterpret_cast<float4*>(&dst[kq * 4 + 0][r4 * 4]) = make_float4(v0.x, v1.x, v2.x, v3.x);
    *reinterpret_cast<float4*>(&dst[kq * 4 + 1][r4 * 4]) = make_float4(v0.y, v1.y, v2.y, v3.y);
    *reinterpret_cast<float4*>(&dst[kq * 4 + 2][r4 * 4]) = make_float4(v0.z, v1.z, v2.z, v3.z);
    *reinterpret_cast<float4*>(&dst[kq * 4 + 3][r4 * 4]) = make_float4(v0.w, v1.w, v2.w, v3.w);
    __syncthreads();
#pragma unroll
    for (int k = 0; k < BK; ++k) {
      const float4 a = *reinterpret_cast<const float4*>(&As[k][ty * 4]);
      const float4 b = *reinterpret_cast<const float4*>(&Bs[k][tx * 4]);
      const float av[4] = {a.x, a.y, a.z, a.w};
      const float bv[4] = {b.x, b.y, b.z, b.w};
#pragma unroll
      for (int i = 0; i < 4; ++i)
#pragma unroll
        for (int j = 0; j < 4; ++j)
          acc[i][j] = fmaf(av[i], bv[j], acc[i][j]);
    }
  }
#pragma unroll
  for (int i = 0; i < 4; ++i) {
    float4 o = {acc[i][0], acc[i][1], acc[i][2], acc[i][3]};
    *reinterpret_cast<float4*>(Lp + (size_t)(bm + ty * 4 + i) * NEXP + bn + tx * 4) = o;
  }
}

// ---------------- Routing: one wave (64 lanes) per token ---------------------
// lane holds experts [4*lane, 4*lane+3]; group g = lanes [8g, 8g+7]
__global__ __launch_bounds__(256) void routing(const float* __restrict__ L,
                                               const float* __restrict__ bias,
                                               float* __restrict__ out,
                                               int nparts) {
  const int lane = threadIdx.x & 63;
  const int tok  = (int)((blockIdx.x * blockDim.x + threadIdx.x) >> 6);
  if (tok >= NTOK) return;

  float4 v = {0.f, 0.f, 0.f, 0.f};
  for (int p = 0; p < nparts; ++p) {
    const float4 t = reinterpret_cast<const float4*>(
        L + (size_t)p * NTOK * NEXP + (size_t)tok * NEXP)[lane];
    v.x += t.x; v.y += t.y; v.z += t.z; v.w += t.w;
  }

  // softmax over 256
  float m = fmaxf(fmaxf(v.x, v.y), fmaxf(v.z, v.w));
#pragma unroll
  for (int off = 32; off; off >>= 1) m = fmaxf(m, __shfl_xor(m, off));
  float s0 = expf(v.x - m), s1 = expf(v.y - m), s2 = expf(v.z - m), s3 = expf(v.w - m);
  float sum = s0 + s1 + s2 + s3;
#pragma unroll
  for (int off = 32; off; off >>= 1) sum += __shfl_xor(sum, off);
  const float inv = 1.0f / sum;
  s0 *= inv; s1 *= inv; s2 *= inv; s3 *= inv;   // original scores

  const float4 bb = reinterpret_cast<const float4*>(bias)[lane];
  float b0 = s0 + bb.x, b1 = s1 + bb.y, b2 = s2 + bb.z, b3 = s3 + bb.w;

  // per-lane top-2 of biased scores, then merge across the 8 lanes of the group
  float m1 = fmaxf(b0, b1), m2 = fminf(b0, b1);
  if (b2 > m1) { m2 = m1; m1 = b2; } else m2 = fmaxf(m2, b2);
  if (b3 > m1) { m2 = m1; m1 = b3; } else m2 = fmaxf(m2, b3);
#pragma unroll
  for (int off = 1; off < 8; off <<= 1) {
    const float o1 = __shfl_xor(m1, off);
    const float o2 = __shfl_xor(m2, off);
    if (o1 > m1) { m2 = fmaxf(m1, o2); m1 = o1; } else m2 = fmaxf(m2, o1);
  }
  const float gscore = m1 + m2;

  float gs[8];
#pragma unroll
  for (int g = 0; g < 8; ++g) gs[g] = __shfl(gscore, g * 8);

  // top-4 groups (strict > keeps lowest index on ties, matching lax.top_k)
  unsigned gsel = 0;
#pragma unroll
  for (int k = 0; k < 4; ++k) {
    float best = -INFINITY; int bi = 0;
#pragma unroll
    for (int g = 0; g < 8; ++g)
      if (!((gsel >> g) & 1u) && gs[g] > best) { best = gs[g]; bi = g; }
    gsel |= 1u << bi;
  }
  if (!((gsel >> (lane >> 3)) & 1u)) { b0 = b1 = b2 = b3 = -INFINITY; }

  // top-8 experts, descending, lowest-index tie-break
  float outw = 0.0f, outi = 0.0f;
  for (int k = 0; k < 8; ++k) {
    float bv = b0; int bi = 0;
    if (b1 > bv) { bv = b1; bi = 1; }
    if (b2 > bv) { bv = b2; bi = 2; }
    if (b3 > bv) { bv = b3; bi = 3; }
    float rv = bv; int ri = lane * 4 + bi;
#pragma unroll
    for (int off = 32; off; off >>= 1) {
      const float ov = __shfl_xor(rv, off);
      const int   oi = __shfl_xor(ri, off);
      if (ov > rv || (ov == rv && oi < ri)) { rv = ov; ri = oi; }
    }
    const int srcl = ri >> 2, slot = ri & 3;
    const float sv = (slot == 0) ? s0 : (slot == 1) ? s1 : (slot == 2) ? s2 : s3;
    const float wsel = __shfl(sv, srcl) * 2.5f;
    if (lane == k) { outw = wsel; outi = (float)ri; }
    if (lane == srcl) {
      if      (slot == 0) b0 = -INFINITY;
      else if (slot == 1) b1 = -INFINITY;
      else if (slot == 2) b2 = -INFINITY;
      else                b3 = -INFINITY;
    }
  }
  if (lane < 8) {
    out[(size_t)tok * 8 + lane] = outw;                       // weights
    out[(size_t)NTOK * 8 + (size_t)tok * 8 + lane] = outi;    // indices (as float)
  }
}

extern "C" void kernel_launch(void* const* d_in, const int* in_sizes, int n_in,
                              void* d_out, int out_size, void* d_ws, size_t ws_size,
                              hipStream_t stream) {
  const float* x    = (const float*)d_in[0];
  const float* w    = (const float*)d_in[1];
  const float* bias = (const float*)d_in[2];
  float* out    = (float*)d_out;
  float* logits = (float*)d_ws;

  const size_t part_bytes = (size_t)NTOK * NEXP * sizeof(float);   // 8 MB
  int nparts = 1;
  if (ws_size >= 4 * part_bytes) nparts = 4;
  else if (ws_size >= 2 * part_bytes) nparts = 2;
  const int tiles_per_part = (DIM / BK) / nparts;   // 224 / nparts

  dim3 gridG(NEXP / BN, NTOK / BM, nparts);   // (4, 128, nparts)
  gemm_f32<<<gridG, 256, 0, stream>>>(x, w, logits, tiles_per_part);

  routing<<<NTOK / 4, 256, 0, stream>>>(logits, bias, out, nparts);
}

// Round 4
// 416.542 us; speedup vs baseline: 1.7032x; 1.6277x over previous
//
#include <hip/hip_runtime.h>
#include <cstddef>
#include <cstdint>

#define DIM   7168
#define NEXP  256
#define NTOK  8192
#define BM    64
#define BK    32

typedef _Float16 f16;
typedef __attribute__((ext_vector_type(8))) _Float16 f16x8;
typedef __attribute__((ext_vector_type(4))) float    f32x4;

// ---------------- W pre-convert: f32 -> f16 hi + f16 lo ---------------------
__global__ __launch_bounds__(256) void wconv(const float* __restrict__ W,
                                             f16* __restrict__ Whi,
                                             f16* __restrict__ Wlo) {
  const int i = (blockIdx.x * 256 + threadIdx.x) * 4;
  const float4 v = *reinterpret_cast<const float4*>(W + i);
  f16 h0 = (f16)v.x, h1 = (f16)v.y, h2 = (f16)v.z, h3 = (f16)v.w;
  f16 l0 = (f16)(v.x - (float)h0), l1 = (f16)(v.y - (float)h1);
  f16 l2 = (f16)(v.z - (float)h2), l3 = (f16)(v.w - (float)h3);
  __attribute__((ext_vector_type(4))) _Float16 hv = {h0, h1, h2, h3};
  __attribute__((ext_vector_type(4))) _Float16 lv = {l0, l1, l2, l3};
  *reinterpret_cast<decltype(hv)*>(Whi + i) = hv;
  *reinterpret_cast<decltype(lv)*>(Wlo + i) = lv;
}

// ---------------- MFMA GEMM: Lp[m][n] = sum_k X[m][k] * W[n][k] -------------
// fp16 3-term split: X=xh+xl, W=wh+wl; acc += xh*wh + xl*wh + xh*wl
// Block: 256 thr (4 waves), tile BM=64 x N=256, wave-tile 64x64, split-K grid.y
__global__ __launch_bounds__(256, 2) void gemm_mfma(const float* __restrict__ X,
                                                    const f16* __restrict__ Whi,
                                                    const f16* __restrict__ Wlo,
                                                    float* __restrict__ L,
                                                    int ktiles) {
  __shared__ __align__(16) f16 Ahi[BM * BK];     // [64][32] f16, 64B rows
  __shared__ __align__(16) f16 Alo[BM * BK];
  __shared__ __align__(16) f16 Bhi[NEXP * BK];   // [256][32] f16
  __shared__ __align__(16) f16 Blo[NEXP * BK];

  const int tid  = threadIdx.x;
  const int lane = tid & 63;
  const int w    = tid >> 6;                 // wave id 0..3 -> output cols w*64
  const int bm   = blockIdx.x * BM;
  const int kbase = blockIdx.y * ktiles * BK;
  float* Lp = L + (size_t)blockIdx.y * NTOK * NEXP;

  // A staging: thread -> row ar (0..63), k-chunk akq (0..3) of 8 f32
  const int ar  = tid >> 2;
  const int akq = tid & 3;
  const float* asrc = X + (size_t)(bm + ar) * DIM + akq * 8;

  // fragment read offsets (f16 elements)
  const int aoff = (lane & 15) * BK + (lane >> 4) * 8;             // + mi*512
  const int boff = (w * 64 + (lane & 15)) * BK + (lane >> 4) * 8;  // + ni*512

  f32x4 acc[4][4];
#pragma unroll
  for (int i = 0; i < 4; ++i)
#pragma unroll
    for (int j = 0; j < 4; ++j) acc[i][j] = 0.0f;

  for (int t = 0; t < ktiles; ++t) {
    const int k0 = kbase + t * BK;

    __syncthreads();   // all waves done reading previous tile

    // B tiles: async global->LDS, 16B per lane, linear dest (4 issues x hi/lo)
#pragma unroll
    for (int j = 0; j < 4; ++j) {
      const int u0 = w * 256 + j * 64;
      const int u  = u0 + lane;
      const size_t goff = (size_t)(u >> 2) * DIM + k0 + (u & 3) * 8;
      __builtin_amdgcn_global_load_lds(
          (const __attribute__((address_space(1))) void*)(Whi + goff),
          (__attribute__((address_space(3))) void*)(&Bhi[u0 * 8]), 16, 0, 0);
      __builtin_amdgcn_global_load_lds(
          (const __attribute__((address_space(1))) void*)(Wlo + goff),
          (__attribute__((address_space(3))) void*)(&Blo[u0 * 8]), 16, 0, 0);
    }

    // A tile: load 8 f32, split to f16 hi/lo, write 16B each
    const float4 a0 = *reinterpret_cast<const float4*>(asrc + k0);
    const float4 a1 = *reinterpret_cast<const float4*>(asrc + k0 + 4);
    const float av[8] = {a0.x, a0.y, a0.z, a0.w, a1.x, a1.y, a1.z, a1.w};
    f16x8 hv, lv;
#pragma unroll
    for (int j = 0; j < 8; ++j) {
      const f16 h = (f16)av[j];
      hv[j] = h;
      lv[j] = (f16)(av[j] - (float)h);
    }
    *reinterpret_cast<f16x8*>(&Ahi[tid * 8]) = hv;
    *reinterpret_cast<f16x8*>(&Alo[tid * 8]) = lv;

    __syncthreads();   // drains vmcnt (gload_lds) + lgkm (A writes)

    f16x8 ah[4], al[4];
#pragma unroll
    for (int mi = 0; mi < 4; ++mi) {
      ah[mi] = *reinterpret_cast<const f16x8*>(&Ahi[mi * 512 + aoff]);
      al[mi] = *reinterpret_cast<const f16x8*>(&Alo[mi * 512 + aoff]);
    }
#pragma unroll
    for (int ni = 0; ni < 4; ++ni) {
      const f16x8 bh = *reinterpret_cast<const f16x8*>(&Bhi[ni * 512 + boff]);
      const f16x8 bl = *reinterpret_cast<const f16x8*>(&Blo[ni * 512 + boff]);
#pragma unroll
      for (int mi = 0; mi < 4; ++mi) {
        acc[mi][ni] = __builtin_amdgcn_mfma_f32_16x16x32_f16(ah[mi], bh, acc[mi][ni], 0, 0, 0);
        acc[mi][ni] = __builtin_amdgcn_mfma_f32_16x16x32_f16(al[mi], bh, acc[mi][ni], 0, 0, 0);
        acc[mi][ni] = __builtin_amdgcn_mfma_f32_16x16x32_f16(ah[mi], bl, acc[mi][ni], 0, 0, 0);
      }
    }
  }

  // epilogue: D col = lane&15, row = (lane>>4)*4 + j
  const int orow0 = bm + (lane >> 4) * 4;
  const int ocol  = w * 64 + (lane & 15);
#pragma unroll
  for (int mi = 0; mi < 4; ++mi)
#pragma unroll
    for (int j = 0; j < 4; ++j) {
      const int row = orow0 + mi * 16 + j;
#pragma unroll
      for (int ni = 0; ni < 4; ++ni)
        Lp[(size_t)row * NEXP + ocol + ni * 16] = acc[mi][ni][j];
    }
}

// ---------------- Routing: one wave (64 lanes) per token ---------------------
__global__ __launch_bounds__(256) void routing(const float* __restrict__ L,
                                               const float* __restrict__ bias,
                                               float* __restrict__ out,
                                               int nparts) {
  const int lane = threadIdx.x & 63;
  const int tok  = (int)((blockIdx.x * blockDim.x + threadIdx.x) >> 6);
  if (tok >= NTOK) return;

  float4 v = {0.f, 0.f, 0.f, 0.f};
  for (int p = 0; p < nparts; ++p) {
    const float4 t = reinterpret_cast<const float4*>(
        L + (size_t)p * NTOK * NEXP + (size_t)tok * NEXP)[lane];
    v.x += t.x; v.y += t.y; v.z += t.z; v.w += t.w;
  }

  float m = fmaxf(fmaxf(v.x, v.y), fmaxf(v.z, v.w));
#pragma unroll
  for (int off = 32; off; off >>= 1) m = fmaxf(m, __shfl_xor(m, off));
  float s0 = expf(v.x - m), s1 = expf(v.y - m), s2 = expf(v.z - m), s3 = expf(v.w - m);
  float sum = s0 + s1 + s2 + s3;
#pragma unroll
  for (int off = 32; off; off >>= 1) sum += __shfl_xor(sum, off);
  const float inv = 1.0f / sum;
  s0 *= inv; s1 *= inv; s2 *= inv; s3 *= inv;

  const float4 bb = reinterpret_cast<const float4*>(bias)[lane];
  float b0 = s0 + bb.x, b1 = s1 + bb.y, b2 = s2 + bb.z, b3 = s3 + bb.w;

  float m1 = fmaxf(b0, b1), m2 = fminf(b0, b1);
  if (b2 > m1) { m2 = m1; m1 = b2; } else m2 = fmaxf(m2, b2);
  if (b3 > m1) { m2 = m1; m1 = b3; } else m2 = fmaxf(m2, b3);
#pragma unroll
  for (int off = 1; off < 8; off <<= 1) {
    const float o1 = __shfl_xor(m1, off);
    const float o2 = __shfl_xor(m2, off);
    if (o1 > m1) { m2 = fmaxf(m1, o2); m1 = o1; } else m2 = fmaxf(m2, o1);
  }
  const float gscore = m1 + m2;

  float gs[8];
#pragma unroll
  for (int g = 0; g < 8; ++g) gs[g] = __shfl(gscore, g * 8);

  unsigned gsel = 0;
#pragma unroll
  for (int k = 0; k < 4; ++k) {
    float best = -INFINITY; int bi = 0;
#pragma unroll
    for (int g = 0; g < 8; ++g)
      if (!((gsel >> g) & 1u) && gs[g] > best) { best = gs[g]; bi = g; }
    gsel |= 1u << bi;
  }
  if (!((gsel >> (lane >> 3)) & 1u)) { b0 = b1 = b2 = b3 = -INFINITY; }

  float outw = 0.0f, outi = 0.0f;
  for (int k = 0; k < 8; ++k) {
    float bv = b0; int bi = 0;
    if (b1 > bv) { bv = b1; bi = 1; }
    if (b2 > bv) { bv = b2; bi = 2; }
    if (b3 > bv) { bv = b3; bi = 3; }
    float rv = bv; int ri = lane * 4 + bi;
#pragma unroll
    for (int off = 32; off; off >>= 1) {
      const float ov = __shfl_xor(rv, off);
      const int   oi = __shfl_xor(ri, off);
      if (ov > rv || (ov == rv && oi < ri)) { rv = ov; ri = oi; }
    }
    const int srcl = ri >> 2, slot = ri & 3;
    const float sv = (slot == 0) ? s0 : (slot == 1) ? s1 : (slot == 2) ? s2 : s3;
    const float wsel = __shfl(sv, srcl) * 2.5f;
    if (lane == k) { outw = wsel; outi = (float)ri; }
    if (lane == srcl) {
      if      (slot == 0) b0 = -INFINITY;
      else if (slot == 1) b1 = -INFINITY;
      else if (slot == 2) b2 = -INFINITY;
      else                b3 = -INFINITY;
    }
  }
  if (lane < 8) {
    out[(size_t)tok * 8 + lane] = outw;
    out[(size_t)NTOK * 8 + (size_t)tok * 8 + lane] = outi;
  }
}

extern "C" void kernel_launch(void* const* d_in, const int* in_sizes, int n_in,
                              void* d_out, int out_size, void* d_ws, size_t ws_size,
                              hipStream_t stream) {
  const float* x    = (const float*)d_in[0];
  const float* w    = (const float*)d_in[1];
  const float* bias = (const float*)d_in[2];
  float* out = (float*)d_out;

  const size_t part_bytes = (size_t)NTOK * NEXP * sizeof(float);     // 8 MB
  const size_t w_bytes    = (size_t)NEXP * DIM * sizeof(f16);        // 3.67 MB each
  int nparts = 1;
  for (int np = 8; np >= 1; np >>= 1)
    if ((size_t)np * part_bytes + 2 * w_bytes <= ws_size) { nparts = np; break; }

  float* logits = (float*)d_ws;
  f16* whi = (f16*)((char*)d_ws + (size_t)nparts * part_bytes);
  f16* wlo = whi + (size_t)NEXP * DIM;

  wconv<<<(NEXP * DIM) / (256 * 4), 256, 0, stream>>>(w, whi, wlo);

  const int ktiles = (DIM / BK) / nparts;   // 224 / nparts
  dim3 gridG(NTOK / BM, nparts);            // (128, nparts)
  gemm_mfma<<<gridG, 256, 0, stream>>>(x, whi, wlo, logits, ktiles);

  routing<<<NTOK / 4, 256, 0, stream>>>(logits, bias, out, nparts);
}